// Round 3
// baseline (323.054 us; speedup 1.0000x reference)
//
#include <hip/hip_runtime.h>
#include <hip/hip_bf16.h>

// Single-head causal attention. B=512, T=256, C=384 (n_embd), H=64.
// scale = C^-0.5 (reference scales by n_embd, NOT head_size).
// Fused: one block = one batch, 16 waves (1024 thr). Phase 1: QKV projection,
// A-frags loaded DIRECT from global (x has no cross-wave reuse -> no x-LDS),
// weights double-buffered in 24 KB LDS via global_load_lds, one barrier/chunk.
// Phase 2: causal attention entirely from LDS fragments.

#define Bsz 512
#define Tt  256
#define Cc  384
#define Hh  64

typedef __attribute__((ext_vector_type(8))) short bf16x8;
typedef __attribute__((ext_vector_type(4))) float f32x4;

__device__ __forceinline__ unsigned short f2bf(float f) {
    unsigned int u = __float_as_uint(f);
    unsigned int r = (u + 0x7fffu + ((u >> 16) & 1u)) >> 16;   // RNE
    return (unsigned short)r;
}
__device__ __forceinline__ float bf2f(unsigned short b) {
    return __uint_as_float(((unsigned int)b) << 16);
}
__device__ __forceinline__ bf16x8 pack8v(f32x4 a, f32x4 b) {
    union { __hip_bfloat162 h2[4]; bf16x8 v; } u;
    u.h2[0] = __float22bfloat162_rn(float2{a[0], a[1]});
    u.h2[1] = __float22bfloat162_rn(float2{a[2], a[3]});
    u.h2[2] = __float22bfloat162_rn(float2{b[0], b[1]});
    u.h2[3] = __float22bfloat162_rn(float2{b[2], b[3]});
    return u.v;
}
// async 16B global->LDS (direct-to-LDS DMA; dest must be uniform base + lane*16)
__device__ __forceinline__ void gload_lds16(const void* g, void* l) {
    __builtin_amdgcn_global_load_lds(
        (const __attribute__((address_space(1))) unsigned int*)g,
        (__attribute__((address_space(3))) unsigned int*)l, 16, 0, 0);
}

// ---------------- kernel 0: weights -> B-fragment order ------------------------
// wtf element ((kc*12+nt)*64 + lane)*8 + j = Wt[n=nt*16+(lane&15)][k=kc*32+(lane>>4)*8+j]
__global__ __launch_bounds__(256) void prep_kernel(const float* __restrict__ Wq,
                                                   const float* __restrict__ Wk,
                                                   const float* __restrict__ Wv,
                                                   unsigned short* __restrict__ wtf) {
    int idx = blockIdx.x * 256 + threadIdx.x;
    if (idx >= 192 * 384) return;
    int j = idx & 7;
    int l = (idx >> 3) & 63;
    int t = idx >> 9;                 // kc*12 + nt
    int kc = t / 12, nt = t - kc * 12;
    int n = nt * 16 + (l & 15);
    int k = kc * 32 + (l >> 4) * 8 + j;
    const float* W = (n < 64) ? Wq : ((n < 128) ? Wk : Wv);
    wtf[idx] = f2bf(W[k * 64 + (n & 63)]);
}

// ---------------- kernel 1: fused QKV + causal attention -----------------------
// 16 waves. Wave w = (wr=w&7, wc=w>>3): rows wr*32 + rt*16 (rt=0,1),
// cols wc*96 + nt*16 (nt=0..5). acc = 48 f32/lane -> VGPR fits 4 waves/SIMD.
// Phase-1 chunk loop: __syncthreads(); stage next weight chunk (DMA) + issue
// next x-loads; compute current. In-flight ops drain at the NEXT barrier
// (a full compute-phase later -> ~free), giving a robust 1-deep pipeline.
// LDS fragment layouts (verified in prior rounds):
//  ql/kl: [tile=row>>4][s=d>>5][lane=((d>>3)&3)*16 + (row&15)][j=d&7]
//  vl:    [ks2=t>>5][ht=d>>4][lane=((t>>3)&3)*16 + (d&15)][j=t&7]
// Phase 2: zero-barrier causal attention; wave w owns q-tile w
// (per-SIMD step totals 16..20 -> balanced). Max-free softmax, divide at end.
__global__ __launch_bounds__(1024, 4) void fused_kernel(
        const float* __restrict__ x,
        const float* __restrict__ bq,
        const float* __restrict__ bk,
        const float* __restrict__ bv,
        const unsigned short* __restrict__ wtf,
        float* __restrict__ out) {
    __shared__ unsigned short kl[16384];      // 32 KB K fragments
    __shared__ unsigned short vl[16384];      // 32 KB V fragments
    __shared__ unsigned short ql[16384];      // 32 KB Q fragments
    __shared__ unsigned short wtl[2][6144];   // 24 KB weight dbuf; phase2: P scratch

    const int tid = threadIdx.x;
    const int w = tid >> 6, lane = tid & 63, quad = lane >> 4, cl = lane & 15;
    const int wr = w & 7, wc = w >> 3;
    const int rb = blockIdx.x * 256;

    f32x4 acc[2][6];
#pragma unroll
    for (int rt = 0; rt < 2; ++rt)
#pragma unroll
        for (int nt = 0; nt < 6; ++nt) acc[rt][nt] = (f32x4){0.f, 0.f, 0.f, 0.f};

    const float* xp0 = x + (size_t)(rb + wr * 32 + cl) * Cc + quad * 8;
    const float* xp1 = xp0 + (size_t)16 * Cc;
    const bool dostage = tid < 768;           // 768 * 16B = 12 KB per chunk
    const unsigned short* wsrc = wtf + tid * 8;
    unsigned short* wdst0 = &wtl[0][tid * 8];
    unsigned short* wdst1 = &wtl[1][tid * 8];

    // prologue: stage chunk 0, issue x-loads for chunk 0
    if (dostage) gload_lds16(wsrc, wdst0);
    f32x4 A0 = *(const f32x4*)(xp0);
    f32x4 A1 = *(const f32x4*)(xp0 + 4);
    f32x4 A2 = *(const f32x4*)(xp1);
    f32x4 A3 = *(const f32x4*)(xp1 + 4);
    f32x4 B0, B1, B2, B3;

#define QKV_COMPUTE(BUF, X0, X1, X2, X3)                                             \
    {                                                                                \
        bf16x8 a0 = pack8v(X0, X1), a1 = pack8v(X2, X3);                             \
        _Pragma("unroll")                                                            \
        for (int nt = 0; nt < 6; ++nt) {                                             \
            bf16x8 bfr = *(const bf16x8*)&wtl[BUF][((wc * 6 + nt) * 64 + lane) * 8]; \
            acc[0][nt] = __builtin_amdgcn_mfma_f32_16x16x32_bf16(a0, bfr, acc[0][nt], 0, 0, 0); \
            acc[1][nt] = __builtin_amdgcn_mfma_f32_16x16x32_bf16(a1, bfr, acc[1][nt], 0, 0, 0); \
        }                                                                            \
    }

    for (int t = 0; t < 6; ++t) {
        const int kc = 2 * t;
        __syncthreads();   // drains last iter's DMA+loads (issued a phase ago: ~free)
        if (dostage) gload_lds16(wsrc + (size_t)(kc + 1) * 6144, wdst1);
        B0 = *(const f32x4*)(xp0 + (kc + 1) * 32);
        B1 = *(const f32x4*)(xp0 + (kc + 1) * 32 + 4);
        B2 = *(const f32x4*)(xp1 + (kc + 1) * 32);
        B3 = *(const f32x4*)(xp1 + (kc + 1) * 32 + 4);
        QKV_COMPUTE(0, A0, A1, A2, A3)
        __syncthreads();
        if (t < 5) {
            if (dostage) gload_lds16(wsrc + (size_t)(kc + 2) * 6144, wdst0);
            A0 = *(const f32x4*)(xp0 + (kc + 2) * 32);
            A1 = *(const f32x4*)(xp0 + (kc + 2) * 32 + 4);
            A2 = *(const f32x4*)(xp1 + (kc + 2) * 32);
            A3 = *(const f32x4*)(xp1 + (kc + 2) * 32 + 4);
        }
        QKV_COMPUTE(1, B0, B1, B2, B3)
    }

    // epilogue: bias + bf16 cast, scatter into LDS fragment buffers
#pragma unroll
    for (int nt = 0; nt < 6; ++nt) {
        const int colbase = wc * 96 + nt * 16;     // wave-uniform
        const int col = colbase + cl;
        if (colbase < 64) {                        // Q columns 0..63
            float bias = bq[col];
            int sh = col >> 5, qp = (col >> 3) & 3, j = col & 7;
#pragma unroll
            for (int rt = 0; rt < 2; ++rt) {
                int m0 = wr * 32 + rt * 16 + quad * 4;
                int basei = (m0 >> 4) * 1024 + sh * 512 + qp * 128 + quad * 32 + j;
#pragma unroll
                for (int r = 0; r < 4; ++r)
                    ql[basei + r * 8] = f2bf(acc[rt][nt][r] + bias);
            }
        } else if (colbase < 128) {                // K columns 64..127
            int h = col - 64;
            float bias = bk[h];
            int sh = h >> 5, qp = (h >> 3) & 3, j = h & 7;
#pragma unroll
            for (int rt = 0; rt < 2; ++rt) {
                int m0 = wr * 32 + rt * 16 + quad * 4;
                int basei = (m0 >> 4) * 1024 + sh * 512 + qp * 128 + quad * 32 + j;
#pragma unroll
                for (int r = 0; r < 4; ++r)
                    kl[basei + r * 8] = f2bf(acc[rt][nt][r] + bias);
            }
        } else {                                   // V columns 128..191
            int h = col - 128;
            float bias = bv[h];
            int ht = h >> 4;
#pragma unroll
            for (int rt = 0; rt < 2; ++rt) {
                int m0 = wr * 32 + rt * 16 + quad * 4;
                int ks2 = m0 >> 5, qp = (m0 >> 3) & 3, j0 = m0 & 7;
                unsigned long long pk =
                      (unsigned long long)f2bf(acc[rt][nt][0] + bias)
                    | ((unsigned long long)f2bf(acc[rt][nt][1] + bias) << 16)
                    | ((unsigned long long)f2bf(acc[rt][nt][2] + bias) << 32)
                    | ((unsigned long long)f2bf(acc[rt][nt][3] + bias) << 48);
                *(unsigned long long*)&vl[(ks2 * 4 + ht) * 512 + qp * 128 + cl * 8 + j0] = pk;
            }
        }
    }
    __syncthreads();   // all Q/K/V fragment writes visible; wtl dead -> P scratch

    // ---------------- phase 2: causal attention from LDS ----------------------
    const float SL2E = 0.07362224f;          // log2(e) / sqrt(384)
    unsigned short* P = &wtl[0][0] + w * 512;   // per-wave 1 KB, overlays dead wtl
    {
        const int W = w;                     // one 16-row q-tile per wave
        const int qrow0 = W * 16;
        bf16x8 aq0 = *(const bf16x8*)&ql[(W * 128 + lane) * 8];
        bf16x8 aq1 = *(const bf16x8*)&ql[(W * 128 + 64 + lane) * 8];

        f32x4 o[4];
#pragma unroll
        for (int ht = 0; ht < 4; ++ht) o[ht] = (f32x4){0.f, 0.f, 0.f, 0.f};
        float rs[4] = {0.f, 0.f, 0.f, 0.f};

        const int nsteps = (qrow0 >> 5) + 1;
        for (int st = 0; st < nsteps; ++st) {
#pragma unroll
            for (int half = 0; half < 2; ++half) {
                int ct = st * 2 + half;      // 16-key tile
                bf16x8 b0 = *(const bf16x8*)&kl[(ct * 128 + lane) * 8];
                bf16x8 b1 = *(const bf16x8*)&kl[(ct * 128 + 64 + lane) * 8];
                f32x4 sc = (f32x4){0.f, 0.f, 0.f, 0.f};
                sc = __builtin_amdgcn_mfma_f32_16x16x32_bf16(aq0, b0, sc, 0, 0, 0);
                sc = __builtin_amdgcn_mfma_f32_16x16x32_bf16(aq1, b1, sc, 0, 0, 0);
                int key = ct * 16 + cl;
#pragma unroll
                for (int r = 0; r < 4; ++r) {
                    int row = quad * 4 + r;
                    float p = (key <= qrow0 + row) ? exp2f(sc[r] * SL2E) : 0.f;
                    unsigned short pb = f2bf(p);
                    rs[r] += bf2f(pb);
                    int k32 = half * 16 + cl;
                    int chunk = (k32 >> 3) ^ quad;           // XOR swizzle (row>>2 == quad)
                    P[row * 32 + chunk * 8 + (k32 & 7)] = pb;
                }
            }
            // prefetch V fragments (overlaps wave-local P drain)
            bf16x8 bvf[4];
#pragma unroll
            for (int ht = 0; ht < 4; ++ht)
                bvf[ht] = *(const bf16x8*)&vl[((st * 4 + ht) * 64 + lane) * 8];

            asm volatile("s_waitcnt lgkmcnt(0)" ::: "memory");   // wave-local P drain
            bf16x8 ap = *(const bf16x8*)((const char*)P + cl * 64 + ((quad ^ (cl >> 2)) & 3) * 16);
#pragma unroll
            for (int ht = 0; ht < 4; ++ht)
                o[ht] = __builtin_amdgcn_mfma_f32_16x16x32_bf16(ap, bvf[ht], o[ht], 0, 0, 0);
        }

        // normalize by row-sum (sum over the 16 key-lanes of each quad) and store
#pragma unroll
        for (int r = 0; r < 4; ++r) {
            float s = rs[r];
            s += __shfl_xor(s, 1);
            s += __shfl_xor(s, 2);
            s += __shfl_xor(s, 4);
            s += __shfl_xor(s, 8);
            float inv = 1.0f / s;
            int t = qrow0 + quad * 4 + r;
#pragma unroll
            for (int ht = 0; ht < 4; ++ht)
                out[((size_t)(blockIdx.x * Tt + t)) * Hh + ht * 16 + cl] = o[ht][r] * inv;
        }
    }
}

// ---------------- launcher ----------------------------------------------------
extern "C" void kernel_launch(void* const* d_in, const int* in_sizes, int n_in,
                              void* d_out, int out_size, void* d_ws, size_t ws_size,
                              hipStream_t stream) {
    const float* x  = (const float*)d_in[0];
    const float* Wq = (const float*)d_in[1];
    const float* bq = (const float*)d_in[2];
    const float* Wk = (const float*)d_in[3];
    const float* bk = (const float*)d_in[4];
    const float* Wv = (const float*)d_in[5];
    const float* bv = (const float*)d_in[6];
    float* out = (float*)d_out;

    unsigned short* wtf = (unsigned short*)d_ws;   // 144 KB fragment-order weights

    prep_kernel<<<288, 256, 0, stream>>>(Wq, Wk, Wv, wtf);
    fused_kernel<<<Bsz, 1024, 0, stream>>>(x, bq, bk, bv, wtf, out);
}

// Round 5
// 314.479 us; speedup vs baseline: 1.0273x; 1.0273x over previous
//
#include <hip/hip_runtime.h>
#include <hip/hip_bf16.h>

// Single-head causal attention. B=512, T=256, C=384 (n_embd), H=64.
// scale = C^-0.5 (reference scales by n_embd, NOT head_size).
// Fused, 2 batches per block, cross-batch pipelined: while batch A runs its
// attention (VALU/MFMA heavy), batch B's QKV staging+MFMA proceeds in the
// same loop -> phase-1 memory latency hides under phase-2 compute.

#define Bsz 512
#define Tt  256
#define Cc  384
#define Hh  64

typedef __attribute__((ext_vector_type(8))) short bf16x8;
typedef __attribute__((ext_vector_type(4))) float f32x4;

__device__ __forceinline__ unsigned short f2bf(float f) {
    unsigned int u = __float_as_uint(f);
    unsigned int r = (u + 0x7fffu + ((u >> 16) & 1u)) >> 16;   // RNE
    return (unsigned short)r;
}
__device__ __forceinline__ float bf2f(unsigned short b) {
    return __uint_as_float(((unsigned int)b) << 16);
}
__device__ __forceinline__ bf16x8 pack8v(f32x4 a, f32x4 b) {
    union { __hip_bfloat162 h2[4]; bf16x8 v; } u;
    u.h2[0] = __float22bfloat162_rn(float2{a[0], a[1]});
    u.h2[1] = __float22bfloat162_rn(float2{a[2], a[3]});
    u.h2[2] = __float22bfloat162_rn(float2{b[0], b[1]});
    u.h2[3] = __float22bfloat162_rn(float2{b[2], b[3]});
    return u.v;
}
// async 16B global->LDS (direct-to-LDS DMA; dest must be uniform base + lane*16)
__device__ __forceinline__ void gload_lds16(const void* g, void* l) {
    __builtin_amdgcn_global_load_lds(
        (const __attribute__((address_space(1))) unsigned int*)g,
        (__attribute__((address_space(3))) unsigned int*)l, 16, 0, 0);
}

// ---------------- kernel 0: weights -> B-fragment order ------------------------
// wtf element ((kc*12+nt)*64 + lane)*8 + j = Wt[n=nt*16+(lane&15)][k=kc*32+(lane>>4)*8+j]
__global__ __launch_bounds__(256) void prep_kernel(const float* __restrict__ Wq,
                                                   const float* __restrict__ Wk,
                                                   const float* __restrict__ Wv,
                                                   unsigned short* __restrict__ wtf) {
    int idx = blockIdx.x * 256 + threadIdx.x;
    if (idx >= 192 * 384) return;
    int j = idx & 7;
    int l = (idx >> 3) & 63;
    int t = idx >> 9;                 // kc*12 + nt
    int kc = t / 12, nt = t - kc * 12;
    int n = nt * 16 + (l & 15);
    int k = kc * 32 + (l >> 4) * 8 + j;
    const float* W = (n < 64) ? Wq : ((n < 128) ? Wk : Wv);
    wtf[idx] = f2bf(W[k * 64 + (n & 63)]);
}

// ---------------- kernel 1: fused QKV + causal attention, 2-batch pipeline -----
// 8 waves (512 thr), 256 blocks, LDS 128 KB -> 1 block/CU, 2 waves/SIMD.
// Wave w: QKV rows w*32..+32, all 12 col-tiles (acc[2][12]); attention q-tiles
// {w, 15-w} = 9 steps + 2 finalizes = 11 slots, run one-per-interleave-slot.
// LDS fragment layouts (verified rounds 0-3):
//  ql/kl: [tile=row>>4][s=d>>5][lane=((d>>3)&3)*16 + (row&15)][j=d&7]
//  vl:    [ks2=t>>5][ht=d>>4][lane=((t>>3)&3)*16 + (d&15)][j=t&7]
__global__ __launch_bounds__(512, 2) void fused_kernel(
        const float* __restrict__ x,
        const float* __restrict__ bq,
        const float* __restrict__ bk,
        const float* __restrict__ bv,
        const unsigned short* __restrict__ wtf,
        float* __restrict__ out) {
    __shared__ unsigned short ql[16384];      // 32 KB Q fragments
    __shared__ unsigned short kl[16384];      // 32 KB K fragments
    __shared__ unsigned short vl[16384];      // 32 KB V fragments
    __shared__ unsigned short wtl[2][6144];   // 24 KB weight chunk double-buffer
    __shared__ unsigned short Pl[8 * 512];    // 8 KB per-wave P round-trip

    const int tid = threadIdx.x;
    const int w = tid >> 6, lane = tid & 63, quad = lane >> 4, cl = lane & 15;
    const int bA = blockIdx.x * 2, bB = bA + 1;
    const float SL2E = 0.07362224f;          // log2(e) / sqrt(384)
    unsigned short* Pw = &Pl[w * 512];

    f32x4 acc[2][12];
    f32x4 Xc0, Xc1, Xc2, Xc3, Xn0, Xn1, Xn2, Xn3;
    // attention state machine (wave-uniform control values)
    int at_ti, at_W, at_qrow0, at_nsteps, at_st;
    bf16x8 at_aq0, at_aq1;
    f32x4 at_o[4];
    float at_rs[4];

#define ZERO_ACC()                                                                   \
    _Pragma("unroll")                                                                \
    for (int rt = 0; rt < 2; ++rt)                                                   \
        _Pragma("unroll")                                                            \
        for (int nt = 0; nt < 12; ++nt) acc[rt][nt] = (f32x4){0.f, 0.f, 0.f, 0.f};

#define STAGE_W(c_) {                                                                \
    const unsigned short* s_ = wtf + (size_t)(c_) * 6144;                            \
    unsigned short* d_ = &wtl[(c_) & 1][0];                                          \
    gload_lds16(s_ + tid * 8, d_ + tid * 8);                                         \
    if (tid < 256) gload_lds16(s_ + (512 + tid) * 8, d_ + (512 + tid) * 8); }

#define XLOAD(Xa, Xb, Xcc, Xd, xp0_, xp1_, k_)                                       \
    Xa = *(const f32x4*)((xp0_) + (k_) * 32);                                        \
    Xb = *(const f32x4*)((xp0_) + (k_) * 32 + 4);                                    \
    Xcc = *(const f32x4*)((xp1_) + (k_) * 32);                                       \
    Xd = *(const f32x4*)((xp1_) + (k_) * 32 + 4);

#define QKV_MFMA(k_) {                                                               \
    bf16x8 a0 = pack8v(Xc0, Xc1), a1 = pack8v(Xc2, Xc3);                             \
    const unsigned short* wb = &wtl[(k_) & 1][0];                                    \
    _Pragma("unroll")                                                                \
    for (int nt = 0; nt < 12; ++nt) {                                                \
        bf16x8 bfr = *(const bf16x8*)&wb[(nt * 64 + lane) * 8];                      \
        acc[0][nt] = __builtin_amdgcn_mfma_f32_16x16x32_bf16(a0, bfr, acc[0][nt], 0, 0, 0); \
        acc[1][nt] = __builtin_amdgcn_mfma_f32_16x16x32_bf16(a1, bfr, acc[1][nt], 0, 0, 0); \
    } }

#define EPILOGUE()                                                                   \
    _Pragma("unroll")                                                                \
    for (int nt = 0; nt < 12; ++nt) {                                                \
        const int col = nt * 16 + cl;                                                \
        if (nt < 4) {                                                                \
            float bias = bq[col];                                                    \
            int sh = col >> 5, qp = (col >> 3) & 3, j = col & 7;                     \
            _Pragma("unroll")                                                        \
            for (int rt = 0; rt < 2; ++rt) {                                         \
                int m0 = w * 32 + rt * 16 + quad * 4;                                \
                int basei = (m0 >> 4) * 1024 + sh * 512 + qp * 128 + quad * 32 + j;  \
                _Pragma("unroll")                                                    \
                for (int r = 0; r < 4; ++r)                                          \
                    ql[basei + r * 8] = f2bf(acc[rt][nt][r] + bias);                 \
            }                                                                        \
        } else if (nt < 8) {                                                         \
            int h = col - 64;                                                        \
            float bias = bk[h];                                                      \
            int sh = h >> 5, qp = (h >> 3) & 3, j = h & 7;                           \
            _Pragma("unroll")                                                        \
            for (int rt = 0; rt < 2; ++rt) {                                         \
                int m0 = w * 32 + rt * 16 + quad * 4;                                \
                int basei = (m0 >> 4) * 1024 + sh * 512 + qp * 128 + quad * 32 + j;  \
                _Pragma("unroll")                                                    \
                for (int r = 0; r < 4; ++r)                                          \
                    kl[basei + r * 8] = f2bf(acc[rt][nt][r] + bias);                 \
            }                                                                        \
        } else {                                                                     \
            int h = col - 128;                                                       \
            float bias = bv[h];                                                      \
            int ht = nt - 8;                                                         \
            _Pragma("unroll")                                                        \
            for (int rt = 0; rt < 2; ++rt) {                                         \
                int m0 = w * 32 + rt * 16 + quad * 4;                                \
                int ks2 = m0 >> 5, qp = (m0 >> 3) & 3, j0 = m0 & 7;                  \
                unsigned long long pk =                                              \
                      (unsigned long long)f2bf(acc[rt][nt][0] + bias)                \
                    | ((unsigned long long)f2bf(acc[rt][nt][1] + bias) << 16)        \
                    | ((unsigned long long)f2bf(acc[rt][nt][2] + bias) << 32)        \
                    | ((unsigned long long)f2bf(acc[rt][nt][3] + bias) << 48);       \
                *(unsigned long long*)&vl[(ks2 * 4 + ht) * 512 + qp * 128 + cl * 8 + j0] = pk; \
            }                                                                        \
        }                                                                            \
    }

#define ATT_INIT()                                                                   \
    at_ti = 0; at_W = w; at_qrow0 = w * 16; at_nsteps = (w >> 1) + 1; at_st = 0;     \
    at_aq0 = *(const bf16x8*)&ql[(at_W * 128 + lane) * 8];                           \
    at_aq1 = *(const bf16x8*)&ql[(at_W * 128 + 64 + lane) * 8];                      \
    at_o[0] = at_o[1] = at_o[2] = at_o[3] = (f32x4){0.f, 0.f, 0.f, 0.f};             \
    at_rs[0] = at_rs[1] = at_rs[2] = at_rs[3] = 0.f;

// one slot of attention work: either one 32-key step or one tile finalize
#define ATT_SLOT(bb)                                                                 \
    if (at_ti < 2) {                                                                 \
        if (at_st < at_nsteps) {                                                     \
            const int st = at_st;                                                    \
            _Pragma("unroll")                                                        \
            for (int half = 0; half < 2; ++half) {                                   \
                int ct = st * 2 + half;                                              \
                bf16x8 b0 = *(const bf16x8*)&kl[(ct * 128 + lane) * 8];              \
                bf16x8 b1 = *(const bf16x8*)&kl[(ct * 128 + 64 + lane) * 8];         \
                f32x4 sc = (f32x4){0.f, 0.f, 0.f, 0.f};                              \
                sc = __builtin_amdgcn_mfma_f32_16x16x32_bf16(at_aq0, b0, sc, 0, 0, 0); \
                sc = __builtin_amdgcn_mfma_f32_16x16x32_bf16(at_aq1, b1, sc, 0, 0, 0); \
                int key = ct * 16 + cl;                                              \
                _Pragma("unroll")                                                    \
                for (int r = 0; r < 4; ++r) {                                        \
                    int row = quad * 4 + r;                                          \
                    float p = (key <= at_qrow0 + row) ? exp2f(sc[r] * SL2E) : 0.f;   \
                    unsigned short pb = f2bf(p);                                     \
                    at_rs[r] += bf2f(pb);                                            \
                    int k32 = half * 16 + cl;                                        \
                    int chunk = (k32 >> 3) ^ quad;                                   \
                    Pw[row * 32 + chunk * 8 + (k32 & 7)] = pb;                       \
                }                                                                    \
            }                                                                        \
            bf16x8 bvf0 = *(const bf16x8*)&vl[((st * 4 + 0) * 64 + lane) * 8];       \
            bf16x8 bvf1 = *(const bf16x8*)&vl[((st * 4 + 1) * 64 + lane) * 8];       \
            bf16x8 bvf2 = *(const bf16x8*)&vl[((st * 4 + 2) * 64 + lane) * 8];       \
            bf16x8 bvf3 = *(const bf16x8*)&vl[((st * 4 + 3) * 64 + lane) * 8];       \
            asm volatile("s_waitcnt lgkmcnt(0)" ::: "memory");                       \
            bf16x8 ap = *(const bf16x8*)((const char*)Pw + cl * 64 + ((quad ^ (cl >> 2)) & 3) * 16); \
            at_o[0] = __builtin_amdgcn_mfma_f32_16x16x32_bf16(ap, bvf0, at_o[0], 0, 0, 0); \
            at_o[1] = __builtin_amdgcn_mfma_f32_16x16x32_bf16(ap, bvf1, at_o[1], 0, 0, 0); \
            at_o[2] = __builtin_amdgcn_mfma_f32_16x16x32_bf16(ap, bvf2, at_o[2], 0, 0, 0); \
            at_o[3] = __builtin_amdgcn_mfma_f32_16x16x32_bf16(ap, bvf3, at_o[3], 0, 0, 0); \
            ++at_st;                                                                 \
        } else {                                                                     \
            _Pragma("unroll")                                                        \
            for (int r = 0; r < 4; ++r) {                                            \
                float s = at_rs[r];                                                  \
                s += __shfl_xor(s, 1);                                               \
                s += __shfl_xor(s, 2);                                               \
                s += __shfl_xor(s, 4);                                               \
                s += __shfl_xor(s, 8);                                               \
                float inv = 1.0f / s;                                                \
                int t = at_qrow0 + quad * 4 + r;                                     \
                _Pragma("unroll")                                                    \
                for (int ht = 0; ht < 4; ++ht)                                       \
                    out[((size_t)((bb) * Tt + t)) * Hh + ht * 16 + cl] = at_o[ht][r] * inv; \
            }                                                                        \
            ++at_ti;                                                                 \
            if (at_ti == 1) {                                                        \
                at_W = 15 - w; at_qrow0 = at_W * 16;                                 \
                at_nsteps = (at_W >> 1) + 1; at_st = 0;                              \
                at_aq0 = *(const bf16x8*)&ql[(at_W * 128 + lane) * 8];               \
                at_aq1 = *(const bf16x8*)&ql[(at_W * 128 + 64 + lane) * 8];          \
                at_o[0] = at_o[1] = at_o[2] = at_o[3] = (f32x4){0.f, 0.f, 0.f, 0.f}; \
                at_rs[0] = at_rs[1] = at_rs[2] = at_rs[3] = 0.f;                     \
            }                                                                        \
        }                                                                            \
    }

    // ================= pass 1: QKV(A), no attention interleave =================
    ZERO_ACC();
    {
        const float* xp0 = x + ((size_t)bA * 256 + w * 32 + cl) * Cc + quad * 8;
        const float* xp1 = xp0 + 16 * Cc;
        STAGE_W(0);
        XLOAD(Xc0, Xc1, Xc2, Xc3, xp0, xp1, 0);
#pragma unroll 1
        for (int k = 0; k < 12; ++k) {
            __syncthreads();   // k=0: prologue DMA visible; k>0: chunk-k DMA visible
            if (k < 11) {
                STAGE_W(k + 1);
                XLOAD(Xn0, Xn1, Xn2, Xn3, xp0, xp1, k + 1);
            }
            QKV_MFMA(k);
            Xc0 = Xn0; Xc1 = Xn1; Xc2 = Xn2; Xc3 = Xn3;
        }
    }

    // issue B's chunk-0 staging + x-loads EARLY (latency hides under epilogue A)
    const float* xpB0 = x + ((size_t)bB * 256 + w * 32 + cl) * Cc + quad * 8;
    const float* xpB1 = xpB0 + 16 * Cc;
    STAGE_W(0);                         // wtl[0] free: last consumed at chunk 10
    XLOAD(Xc0, Xc1, Xc2, Xc3, xpB0, xpB1, 0);

    EPILOGUE();                         // scatter A's q/k/v fragments (reads acc)
    ZERO_ACC();                         // reset acc for B
    __syncthreads();                    // epilogue-A + B chunk-0 DMA visible

    // ============== pass 2: attention(A) interleaved with QKV(B) ===============
    ATT_INIT();
#pragma unroll 1
    for (int k = 0; k < 12; ++k) {
        if (k) __syncthreads();         // chunk-k DMA visible (k=0 covered above)
        if (k < 11) {
            STAGE_W(k + 1);
            XLOAD(Xn0, Xn1, Xn2, Xn3, xpB0, xpB1, k + 1);
        }
        ATT_SLOT(bA);                   // 11 real slots (9 steps + 2 finalizes)
        QKV_MFMA(k);
        Xc0 = Xn0; Xc1 = Xn1; Xc2 = Xn2; Xc3 = Xn3;
    }

    // epilogue B: safe without extra barrier — slot-11's top barrier guarantees
    // all waves finished slot 10, and the last ql/kl/vl reads happen by slot 9.
    EPILOGUE();
    __syncthreads();                    // B fragments visible to all waves

    // ================= pass 3: attention(B), straight-line =====================
    ATT_INIT();
#pragma unroll 1
    for (int sl = 0; sl < 11; ++sl) {
        ATT_SLOT(bB);
    }
}

// ---------------- launcher ----------------------------------------------------
extern "C" void kernel_launch(void* const* d_in, const int* in_sizes, int n_in,
                              void* d_out, int out_size, void* d_ws, size_t ws_size,
                              hipStream_t stream) {
    const float* x  = (const float*)d_in[0];
    const float* Wq = (const float*)d_in[1];
    const float* bq = (const float*)d_in[2];
    const float* Wk = (const float*)d_in[3];
    const float* bk = (const float*)d_in[4];
    const float* Wv = (const float*)d_in[5];
    const float* bv = (const float*)d_in[6];
    float* out = (float*)d_out;

    unsigned short* wtf = (unsigned short*)d_ws;   // 144 KB fragment-order weights

    prep_kernel<<<288, 256, 0, stream>>>(Wq, Wk, Wv, wtf);
    fused_kernel<<<256, 512, 0, stream>>>(x, bq, bk, bv, wtf, out);
}